// Round 9
// baseline (273.932 us; speedup 1.0000x reference)
//
#include <hip/hip_runtime.h>
#include <hip/hip_bf16.h>
#include <hip/hip_fp16.h>
#include <math.h>

#define B_ 2
#define L_ 2048
#define DM_ 512
#define H_ 8
#define DK_ 64
// exp2-domain: fold log2(e) into the Q scale so softmax uses exp2 directly
#define SCALE2_ (0.125f * 1.44269504088896f)
#define KSPLIT 4
#define KTILES (L_ / 64 / KSPLIT)   // 8 key-tiles per split
#define THR_ 11.5f                  // defer-max threshold (log2 units ~ 8 nats)

typedef __attribute__((ext_vector_type(8))) short short8;      // MFMA bf16 A/B frag
typedef __attribute__((ext_vector_type(8))) unsigned short ushort8;
typedef __attribute__((ext_vector_type(4))) float f32x4;       // MFMA C/D frag 16x16
typedef __attribute__((ext_vector_type(16))) float f32x16;     // MFMA C/D frag 32x32
typedef __attribute__((ext_vector_type(4))) unsigned u32x4;
typedef unsigned short u16;
typedef unsigned u32;

__device__ __forceinline__ u16 f2bf(float x) {
    __hip_bfloat16 h = __float2bfloat16(x);
    u16 r; __builtin_memcpy(&r, &h, 2); return r;
}
__device__ __forceinline__ u16 f2h(float x) {
    __half h = __float2half(x);
    u16 r; __builtin_memcpy(&r, &h, 2); return r;
}
__device__ __forceinline__ float h2f(u16 v) {
    __half h; __builtin_memcpy(&h, &v, 2); return __half2float(h);
}
__device__ __forceinline__ short8 pack8(float4 a, float4 b) {
    ushort8 o;
    o[0]=f2bf(a.x); o[1]=f2bf(a.y); o[2]=f2bf(a.z); o[3]=f2bf(a.w);
    o[4]=f2bf(b.x); o[5]=f2bf(b.y); o[6]=f2bf(b.z); o[7]=f2bf(b.w);
    return __builtin_bit_cast(short8, o);
}

// async global->LDS, 16B/lane; LDS dest is wave-uniform base + laneInWave*16
__device__ __forceinline__ void gld16(const u16* g, u16* l) {
    __builtin_amdgcn_global_load_lds(
        (const __attribute__((address_space(1))) void*)g,
        (__attribute__((address_space(3))) void*)l, 16, 0, 0);
}

// ---------------------------------------------------------------------------
// Fused Q/K/V projection GEMM with INLINE fp32->bf16 conversion.
// (UNCHANGED from round 8.)
// ---------------------------------------------------------------------------
__global__ __launch_bounds__(256)
void proj3(const float* __restrict__ Xq, const float* __restrict__ Xk,
           const float* __restrict__ Xv, const float* __restrict__ Wq,
           const float* __restrict__ Wk, const float* __restrict__ Wv,
           const float* __restrict__ bq, const float* __restrict__ bk,
           const float* __restrict__ bv, u16* __restrict__ qw,
           u16* __restrict__ kw, u16* __restrict__ vtw)
{
    __shared__ u16 As[2][128*64];
    __shared__ u16 Bs[2][128*64];

    const int z = blockIdx.z;
    const float* X = (z==0) ? Xq : (z==1) ? Xk : Xv;
    const float* W = (z==0) ? Wq : (z==1) ? Wk : Wv;
    const float* bias = (z==0) ? bq : (z==1) ? bk : bv;

    const int t = threadIdx.x;
    const int w = t >> 6, lw = t & 63;
    const int g = lw >> 4, c15 = lw & 15;
    const int wx = w & 1, wy = w >> 1;
    const int m0 = blockIdx.x * 128, n0 = blockIdx.y * 128;
    const int rs0 = w*8 + (lw >> 3);
    const int cs0 = lw & 7;

    f32x4 acc[4][4];
    #pragma unroll
    for (int mi = 0; mi < 4; ++mi)
        #pragma unroll
        for (int ni = 0; ni < 4; ++ni) acc[mi][ni] = f32x4{0.f,0.f,0.f,0.f};

    float4 xa[4][2], wa[4][2];

    #pragma unroll
    for (int j = 0; j < 4; ++j) {
        const int r = rs0 + j*32;
        const int c8 = (cs0 ^ (r & 7)) * 8;
        xa[j][0] = *(const float4*)&X[(size_t)(m0 + r)*DM_ + c8];
        xa[j][1] = *(const float4*)&X[(size_t)(m0 + r)*DM_ + c8 + 4];
        wa[j][0] = *(const float4*)&W[(size_t)(n0 + r)*DM_ + c8];
        wa[j][1] = *(const float4*)&W[(size_t)(n0 + r)*DM_ + c8 + 4];
    }
    #pragma unroll
    for (int j = 0; j < 4; ++j) {
        *(short8*)&As[0][w*512 + j*2048 + lw*8] = pack8(xa[j][0], xa[j][1]);
        *(short8*)&Bs[0][w*512 + j*2048 + lw*8] = pack8(wa[j][0], wa[j][1]);
    }
    __syncthreads();

    int buf = 0;
    for (int k0 = 0; k0 < DM_; k0 += 64) {
        const bool nxt = (k0 + 64 < DM_);
        if (nxt) {
            #pragma unroll
            for (int j = 0; j < 4; ++j) {
                const int r = rs0 + j*32;
                const int c8 = (cs0 ^ (r & 7)) * 8;
                xa[j][0] = *(const float4*)&X[(size_t)(m0 + r)*DM_ + k0 + 64 + c8];
                xa[j][1] = *(const float4*)&X[(size_t)(m0 + r)*DM_ + k0 + 64 + c8 + 4];
                wa[j][0] = *(const float4*)&W[(size_t)(n0 + r)*DM_ + k0 + 64 + c8];
                wa[j][1] = *(const float4*)&W[(size_t)(n0 + r)*DM_ + k0 + 64 + c8 + 4];
            }
        }
        #pragma unroll
        for (int ks = 0; ks < 2; ++ks) {
            short8 af[4], bf[4];
            #pragma unroll
            for (int mi = 0; mi < 4; ++mi) {
                const int ar = wy*64 + mi*16 + c15;
                af[mi] = *(const short8*)&As[buf][ar*64 + (((ks*4 + g) ^ (ar & 7)) * 8)];
            }
            #pragma unroll
            for (int ni = 0; ni < 4; ++ni) {
                const int br = wx*64 + ni*16 + c15;
                bf[ni] = *(const short8*)&Bs[buf][br*64 + (((ks*4 + g) ^ (br & 7)) * 8)];
            }
            #pragma unroll
            for (int mi = 0; mi < 4; ++mi)
                #pragma unroll
                for (int ni = 0; ni < 4; ++ni)
                    acc[mi][ni] = __builtin_amdgcn_mfma_f32_16x16x32_bf16(
                        af[mi], bf[ni], acc[mi][ni], 0, 0, 0);
        }
        if (nxt) {
            #pragma unroll
            for (int j = 0; j < 4; ++j) {
                *(short8*)&As[buf^1][w*512 + j*2048 + lw*8] = pack8(xa[j][0], xa[j][1]);
                *(short8*)&Bs[buf^1][w*512 + j*2048 + lw*8] = pack8(wa[j][0], wa[j][1]);
            }
        }
        __syncthreads();
        buf ^= 1;
    }

    const int bb = m0 >> 11;
    const int l0 = m0 & (L_ - 1);
    if (z < 2) {
        u16* out = (z == 0) ? qw : kw;
        const float sc = (z == 0) ? SCALE2_ : 1.0f;
        #pragma unroll
        for (int ni = 0; ni < 4; ++ni) {
            const int n = n0 + wx*64 + ni*16 + c15;
            const int h = n >> 6, dk = n & 63;
            const float bv2 = bias[n];
            #pragma unroll
            for (int mi = 0; mi < 4; ++mi) {
                #pragma unroll
                for (int reg = 0; reg < 4; ++reg) {
                    const int l = l0 + wy*64 + mi*16 + 4*g + reg;
                    out[(((size_t)bb*H_ + h)*L_ + l)*DK_ + dk] =
                        f2bf((acc[mi][ni][reg] + bv2) * sc);
                }
            }
        }
    } else {
        #pragma unroll
        for (int ni = 0; ni < 4; ++ni) {
            const int n = n0 + wx*64 + ni*16 + c15;
            const int h = n >> 6, dk = n & 63;
            const float bv2 = bias[n];
            #pragma unroll
            for (int mi = 0; mi < 4; ++mi) {
                const int l = l0 + wy*64 + mi*16 + 4*g;
                ushort4 o4;
                o4.x = f2bf(acc[mi][ni][0] + bv2);
                o4.y = f2bf(acc[mi][ni][1] + bv2);
                o4.z = f2bf(acc[mi][ni][2] + bv2);
                o4.w = f2bf(acc[mi][ni][3] + bv2);
                *(ushort4*)&vtw[(((size_t)bb*H_ + h)*DK_ + dk)*L_ + l] = o4;
            }
        }
    }
}

// ---------------------------------------------------------------------------
// Flash attention v5: 32x32 swapped MFMA, VALU-lean softmax.
//  - C-init = -m_run: S-MFMA emits (S - m) directly (per-lane = per-q); the
//    32 subs/tile vanish on the common path. m_run init 0 (NOT -inf: the
//    C-init trick needs |m| small; with these scores rescale ~never fires).
//  - 2-tile hand-unrolled loop: buf is compile-time -> all swizzled LDS read
//    addresses loop-invariant; staging pointers advance additively.
//  - Tree reductions (4 chains) for max and sum.
//  - s_setprio(1) around MFMA clusters (T5).
// Grid (bh=16, qt=16, ks=4) = 1024 blocks, 4 waves.
// Oph f16 normalized partials + ml (m,l) — format unchanged.
// ---------------------------------------------------------------------------
__global__ __launch_bounds__(256, 4)
void attn2(const u16* __restrict__ qg, const u16* __restrict__ kg,
           const u16* __restrict__ vtg, u16* __restrict__ Oph,
           float2* __restrict__ ml)
{
    __shared__ char smem[34816];            // 32KB K/V dbuf; 34KB transpose after
    u16* KsB = (u16*)smem;                  // [2][64*64]
    u16* VsB = (u16*)(smem + 16384);        // [2][64*64]

    const int t  = threadIdx.x;
    const int w  = t >> 6, lw = t & 63;
    const int lq = lw & 31;
    const int hi = lw >> 5;
    const int bh = blockIdx.x, qt = blockIdx.y, ksp = blockIdx.z;

    const u16* kp = kg + (size_t)bh*L_*DK_;
    const u16* vp = vtg + (size_t)bh*DK_*L_;
    const int qglob = qt*128 + w*32 + lq;

    short8 qf[4];
    {
        const u16* qp = qg + ((size_t)bh*L_ + qglob) * DK_;
        #pragma unroll
        for (int st = 0; st < 4; ++st)
            qf[st] = *(const short8*)&qp[st*16 + hi*8];
    }

    f32x16 oacc[2];
    #pragma unroll
    for (int dt = 0; dt < 2; ++dt)
        #pragma unroll
        for (int r = 0; r < 16; ++r) oacc[dt][r] = 0.f;
    float m_run = 0.f, l_run = 0.f;     // m starts at 0 (see header comment)

    const int rs0 = w*8 + (lw >> 3);
    const int cs0 = lw & 7;

    // staging source pointers for this lane (advance additively per tile)
    const int kt0 = ksp * KTILES;
    const u16* kst0 = kp + (size_t)(kt0*64 + rs0)*DK_ + ((cs0 ^ (rs0 & 7)) * 8);
    const u16* kst1 = kp + (size_t)(kt0*64 + rs0 + 32)*DK_ + ((cs0 ^ ((rs0 + 32) & 7)) * 8);
    const u16* vst0 = vp + (size_t)rs0*L_ + kt0*64 + ((cs0 ^ (rs0 & 7)) * 8);
    const u16* vst1 = vp + (size_t)(rs0 + 32)*L_ + kt0*64 + ((cs0 ^ ((rs0 + 32) & 7)) * 8);

    // prologue: stage first tile into buf 0
    gld16(kst0, KsB + w*512);
    gld16(kst1, KsB + 2048 + w*512);
    gld16(vst0, VsB + w*512);
    gld16(vst1, VsB + 2048 + w*512);
    kst0 += 64*DK_; kst1 += 64*DK_; vst0 += 64; vst1 += 64;
    __syncthreads();

    // one K/V tile: stage next into bufc^1 (if ds), compute on bufc, barrier
    auto tile_step = [&](int bufc, bool ds) {
        if (ds) {
            gld16(kst0, KsB + (bufc^1)*4096 + w*512);
            gld16(kst1, KsB + (bufc^1)*4096 + 2048 + w*512);
            gld16(vst0, VsB + (bufc^1)*4096 + w*512);
            gld16(vst1, VsB + (bufc^1)*4096 + 2048 + w*512);
            kst0 += 64*DK_; kst1 += 64*DK_; vst0 += 64; vst1 += 64;
        }
        const u16* Ks = KsB + bufc*4096;
        const u16* Vs = VsB + bufc*4096;

        // ---- S^T - m = mfma(K, Q) with C initialized to -m_run
        f32x16 sacc[2];
        #pragma unroll
        for (int nt = 0; nt < 2; ++nt)
            #pragma unroll
            for (int r = 0; r < 16; ++r) sacc[nt][r] = -m_run;
        __builtin_amdgcn_s_setprio(1);
        #pragma unroll
        for (int st = 0; st < 4; ++st) {
            #pragma unroll
            for (int nt = 0; nt < 2; ++nt) {
                const int key = nt*32 + lq;
                short8 kf = *(const short8*)&Ks[key*64 + (((2*st + hi) ^ (key & 7)) * 8)];
                sacc[nt] = __builtin_amdgcn_mfma_f32_32x32x16_bf16(
                    kf, qf[st], sacc[nt], 0, 0, 0);
            }
        }
        __builtin_amdgcn_s_setprio(0);

        // ---- tree max over the 32 local (S - m) values
        float mx[4];
        #pragma unroll
        for (int c = 0; c < 4; ++c)
            mx[c] = fmaxf(fmaxf(sacc[0][c], sacc[0][c+4]),
                          fmaxf(sacc[0][c+8], sacc[0][c+12]));
        #pragma unroll
        for (int c = 0; c < 4; ++c)
            mx[c] = fmaxf(mx[c], fmaxf(fmaxf(sacc[1][c], sacc[1][c+4]),
                                       fmaxf(sacc[1][c+8], sacc[1][c+12])));
        float tmaxd = fmaxf(fmaxf(mx[0], mx[1]), fmaxf(mx[2], mx[3]));
        tmaxd = fmaxf(tmaxd, __shfl_xor(tmaxd, 32, 64));

        float ps[4] = {0.f, 0.f, 0.f, 0.f};
        if (__builtin_expect(__all(tmaxd <= THR_), 1)) {
            // common path: P = exp2(S - m), no subtraction needed
            #pragma unroll
            for (int nt = 0; nt < 2; ++nt)
                #pragma unroll
                for (int r = 0; r < 16; ++r) {
                    const float p = exp2f(sacc[nt][r]);
                    sacc[nt][r] = p;
                    ps[r & 3] += p;
                }
        } else {
            // rare: new max exceeds old by delta -> rescale
            const float delta = fmaxf(tmaxd, 0.f);
            const float fr = exp2f(-delta);
            m_run += delta;
            l_run *= fr;
            #pragma unroll
            for (int dt = 0; dt < 2; ++dt)
                oacc[dt] = oacc[dt] * fr;
            #pragma unroll
            for (int nt = 0; nt < 2; ++nt)
                #pragma unroll
                for (int r = 0; r < 16; ++r) {
                    const float p = exp2f(sacc[nt][r] - delta);
                    sacc[nt][r] = p;
                    ps[r & 3] += p;
                }
        }
        l_run += (ps[0] + ps[1]) + (ps[2] + ps[3]);

        // ---- pack P -> bf16 pairs
        u32 pk[2][4][2];
        #pragma unroll
        for (int nt = 0; nt < 2; ++nt)
            #pragma unroll
            for (int mp = 0; mp < 4; ++mp)
                #pragma unroll
                for (int pp = 0; pp < 2; ++pp)
                    pk[nt][mp][pp] = (u32)f2bf(sacc[nt][4*mp + 2*pp])
                                   | ((u32)f2bf(sacc[nt][4*mp + 2*pp + 1]) << 16);

        // ---- PV: O^T = mfma(V^T, P^T) with lane-32 exchange (validated r6/r7)
        #pragma unroll
        for (int ks = 0; ks < 4; ++ks) {
            const int nt = ks >> 1, bsel = ks & 1;
            u32 pass0 = hi ? pk[nt][2*bsel][0] : pk[nt][2*bsel+1][0];
            u32 pass1 = hi ? pk[nt][2*bsel][1] : pk[nt][2*bsel+1][1];
            u32 r0 = __shfl_xor(pass0, 32, 64);
            u32 r1 = __shfl_xor(pass1, 32, 64);
            u32x4 pw;
            pw[0] = hi ? r0 : pk[nt][2*bsel][0];
            pw[1] = hi ? r1 : pk[nt][2*bsel][1];
            pw[2] = hi ? pk[nt][2*bsel+1][0] : r0;
            pw[3] = hi ? pk[nt][2*bsel+1][1] : r1;
            short8 pb = __builtin_bit_cast(short8, pw);
            __builtin_amdgcn_s_setprio(1);
            #pragma unroll
            for (int dt = 0; dt < 2; ++dt) {
                const int d = dt*32 + lq;
                short8 vf = *(const short8*)&Vs[d*64 + (((2*ks + hi) ^ (d & 7)) * 8)];
                oacc[dt] = __builtin_amdgcn_mfma_f32_32x32x16_bf16(
                    vf, pb, oacc[dt], 0, 0, 0);
            }
            __builtin_amdgcn_s_setprio(0);
        }

        __syncthreads();
    };

    // KTILES = 8: four hand-unrolled buf0/buf1 pairs (compile-time buf)
    tile_step(0, true);  tile_step(1, true);
    tile_step(0, true);  tile_step(1, true);
    tile_step(0, true);  tile_step(1, true);
    tile_step(0, true);  tile_step(1, false);

    // ---- epilogue: normalize, transpose O^T[d][q] -> [q][d], store f16
    const float l_tot = l_run + __shfl_xor(l_run, 32, 64);
    const float inv = 1.0f / l_tot;
    __syncthreads();   // all waves done with K/V LDS
    float* tw = (float*)smem + w * 2176;   // 32 rows x 68 floats per wave
    #pragma unroll
    for (int dt = 0; dt < 2; ++dt)
        #pragma unroll
        for (int r = 0; r < 16; ++r) {
            const int d = dt*32 + (r & 3) + 8*(r >> 2) + 4*hi;
            tw[lq*68 + d] = oacc[dt][r] * inv;
        }
    u16* op = Oph + ((size_t)(ksp*16 + bh)*L_ + qglob)*DK_;
    #pragma unroll
    for (int p4 = 0; p4 < 8; ++p4) {
        const int d0 = hi*32 + p4*4;
        float4 v = *(const float4*)&tw[lq*68 + d0];
        ushort4 o4;
        o4.x = f2h(v.x); o4.y = f2h(v.y); o4.z = f2h(v.z); o4.w = f2h(v.w);
        *(ushort4*)&op[d0] = o4;
    }
    if (hi == 0)
        ml[((size_t)ksp*16 + bh)*L_ + qglob] = float2{m_run, l_tot};
}

// ---------------------------------------------------------------------------
// Combine 4 normalized f16 splits -> bf16 context cw. (UNCHANGED)
// ---------------------------------------------------------------------------
__global__ __launch_bounds__(256)
void combine(const u16* __restrict__ Oph, const float2* __restrict__ ml,
             u16* __restrict__ cw)
{
    const int t = threadIdx.x;
    const size_t row = (size_t)blockIdx.x*16 + (t >> 4);  // bh*L + l, 0..32767
    const int di = (t & 15) * 4;

    float2 a[KSPLIT];
    #pragma unroll
    for (int s = 0; s < KSPLIT; ++s) a[s] = ml[row + (size_t)s*32768];
    float M = a[0].x;
    #pragma unroll
    for (int s = 1; s < KSPLIT; ++s) M = fmaxf(M, a[s].x);
    float ws[KSPLIT], den = 0.f;
    #pragma unroll
    for (int s = 0; s < KSPLIT; ++s) { ws[s] = a[s].y * exp2f(a[s].x - M); den += ws[s]; }
    const float inv = 1.0f / den;

    float acc0 = 0.f, acc1 = 0.f, acc2 = 0.f, acc3 = 0.f;
    #pragma unroll
    for (int s = 0; s < KSPLIT; ++s) {
        ushort4 v = *(const ushort4*)&Oph[(row + (size_t)s*32768)*DK_ + di];
        acc0 += ws[s] * h2f(v.x);
        acc1 += ws[s] * h2f(v.y);
        acc2 += ws[s] * h2f(v.z);
        acc3 += ws[s] * h2f(v.w);
    }
    const int bh = (int)(row >> 11), l = (int)(row & 2047);
    const int bb = bh >> 3, h = bh & 7;
    ushort4 o4;
    o4.x = f2bf(acc0 * inv);
    o4.y = f2bf(acc1 * inv);
    o4.z = f2bf(acc2 * inv);
    o4.w = f2bf(acc3 * inv);
    *(ushort4*)&cw[((size_t)bb*L_ + l)*DM_ + h*DK_ + di] = o4;
}

// ---------------------------------------------------------------------------
// Final projection: out = cw @ Wo^T + bo, fp32 out. (UNCHANGED)
// ---------------------------------------------------------------------------
__global__ __launch_bounds__(256)
void gemmO(const u16* __restrict__ X, const float* __restrict__ W,
           const float* __restrict__ bias, float* __restrict__ out)
{
    __shared__ u16 As[2][128*64];
    __shared__ u16 Bs[2][128*64];

    const int t = threadIdx.x;
    const int w = t >> 6, lw = t & 63;
    const int g = lw >> 4, c15 = lw & 15;
    const int wx = w & 1, wy = w >> 1;
    const int m0 = blockIdx.x * 128, n0 = blockIdx.y * 128;
    const int rs0 = w*8 + (lw >> 3);
    const int cs0 = lw & 7;

    f32x4 acc[4][4];
    #pragma unroll
    for (int mi = 0; mi < 4; ++mi)
        #pragma unroll
        for (int ni = 0; ni < 4; ++ni) acc[mi][ni] = f32x4{0.f,0.f,0.f,0.f};

    float4 wa[4][2];
    #pragma unroll
    for (int j = 0; j < 4; ++j) {
        const int r = rs0 + j*32;
        const int c8 = (cs0 ^ (r & 7)) * 8;
        gld16(X + (size_t)(m0 + r)*DM_ + c8, &As[0][w*512 + j*2048]);
        wa[j][0] = *(const float4*)&W[(size_t)(n0 + r)*DM_ + c8];
        wa[j][1] = *(const float4*)&W[(size_t)(n0 + r)*DM_ + c8 + 4];
    }
    #pragma unroll
    for (int j = 0; j < 4; ++j)
        *(short8*)&Bs[0][w*512 + j*2048 + lw*8] = pack8(wa[j][0], wa[j][1]);
    __syncthreads();

    int buf = 0;
    for (int k0 = 0; k0 < DM_; k0 += 64) {
        const bool nxt = (k0 + 64 < DM_);
        if (nxt) {
            #pragma unroll
            for (int j = 0; j < 4; ++j) {
                const int r = rs0 + j*32;
                const int c8 = (cs0 ^ (r & 7)) * 8;
                gld16(X + (size_t)(m0 + r)*DM_ + k0 + 64 + c8, &As[buf^1][w*512 + j*2048]);
                wa[j][0] = *(const float4*)&W[(size_t)(n0 + r)*DM_ + k0 + 64 + c8];
                wa[j][1] = *(const float4*)&W[(size_t)(n0 + r)*DM_ + k0 + 64 + c8 + 4];
            }
        }
        #pragma unroll
        for (int ks = 0; ks < 2; ++ks) {
            short8 af[4], bf[4];
            #pragma unroll
            for (int mi = 0; mi < 4; ++mi) {
                const int ar = wy*64 + mi*16 + c15;
                af[mi] = *(const short8*)&As[buf][ar*64 + (((ks*4 + g) ^ (ar & 7)) * 8)];
            }
            #pragma unroll
            for (int ni = 0; ni < 4; ++ni) {
                const int br = wx*64 + ni*16 + c15;
                bf[ni] = *(const short8*)&Bs[buf][br*64 + (((ks*4 + g) ^ (br & 7)) * 8)];
            }
            #pragma unroll
            for (int mi = 0; mi < 4; ++mi)
                #pragma unroll
                for (int ni = 0; ni < 4; ++ni)
                    acc[mi][ni] = __builtin_amdgcn_mfma_f32_16x16x32_bf16(
                        af[mi], bf[ni], acc[mi][ni], 0, 0, 0);
        }
        if (nxt) {
            #pragma unroll
            for (int j = 0; j < 4; ++j)
                *(short8*)&Bs[buf^1][w*512 + j*2048 + lw*8] = pack8(wa[j][0], wa[j][1]);
        }
        __syncthreads();
        buf ^= 1;
    }

    #pragma unroll
    for (int ni = 0; ni < 4; ++ni) {
        const int n = n0 + wx*64 + ni*16 + c15;
        const float bv = bias[n];
        #pragma unroll
        for (int mi = 0; mi < 4; ++mi) {
            #pragma unroll
            for (int reg = 0; reg < 4; ++reg) {
                const int m = m0 + wy*64 + mi*16 + 4*g + reg;
                out[(size_t)m * DM_ + n] = acc[mi][ni][reg] + bv;
            }
        }
    }
}

// ---------------------------------------------------------------------------
extern "C" void kernel_launch(void* const* d_in, const int* in_sizes, int n_in,
                              void* d_out, int out_size, void* d_ws, size_t ws_size,
                              hipStream_t stream)
{
    const float* Q  = (const float*)d_in[0];
    const float* K  = (const float*)d_in[1];
    const float* V  = (const float*)d_in[2];
    const float* Wq = (const float*)d_in[3];
    const float* bq = (const float*)d_in[4];
    const float* Wk = (const float*)d_in[5];
    const float* bk = (const float*)d_in[6];
    const float* Wv = (const float*)d_in[7];
    const float* bv = (const float*)d_in[8];
    const float* Wo = (const float*)d_in[9];
    const float* bo = (const float*)d_in[10];
    // d_in[11] = index_sample: provably unused (n_top == L -> top_k is a
    // permutation -> the scatter overwrites the whole mean-context baseline).

    char* w8 = (char*)d_ws;
    const size_t MB = 1u << 20;
    u16*    Oph = (u16*)(w8);                    // f16 [4][16][2048][64] = 16MB
    float2* ml  = (float2*)(w8 + 16*MB);         // 1MB
    u16*    qw  = (u16*)(w8 + 17*MB);            // [B,H,L,DK] bf16, *SCALE2_
    u16*    kw  = (u16*)(w8 + 21*MB);
    u16*    vtw = (u16*)(w8 + 25*MB);            // [B,H,DK,L] bf16 (ends 29MB)
    u16*    cw  = (u16*)(w8 + 17*MB);            // ALIAS qw (dead after attn)

    dim3 blk(256);
    proj3<<<dim3(32, 4, 3), blk, 0, stream>>>(Q, K, V, Wq, Wk, Wv,
                                              bq, bk, bv, qw, kw, vtw);

    attn2<<<dim3(16, 16, KSPLIT), blk, 0, stream>>>(qw, kw, vtw, Oph, ml);

    combine<<<2048, blk, 0, stream>>>(Oph, ml, cw);

    gemmO<<<dim3(32, 4), blk, 0, stream>>>(cw, Wo, bo, (float*)d_out);
}